// Round 9
// baseline (533.526 us; speedup 1.0000x reference)
//
#include <hip/hip_runtime.h>
#include <math.h>

typedef _Float16 f16;
typedef _Float16 f16x8 __attribute__((ext_vector_type(8)));
typedef _Float16 f16x4 __attribute__((ext_vector_type(4)));
typedef float f32x4 __attribute__((ext_vector_type(4)));

#define NROWS 12288
#define NFEAT 4096
#define DDIM  256
#define KDIM  1000
#define KPAD  1024

// workspace layout (bytes)
static const size_t OFF_A16 = 0;           // 12288*256 f16 = 6,291,456
static const size_t OFF_BF  = 6291456;     // 1024*256 f16  =   524,288
static const size_t OFF_E16 = 6815744;     // 12288*1024 f16= 25,165,824
static const size_t OFF_P0  = 31981568;    // 96*1024 f32
static const size_t OFF_P1  = 32374784;    // 768*1024 f32
static const size_t OFF_P2  = 35520512;    // 768*1024 f32
static const size_t OFF_G1  = 38666240;    // 64*1024 f32
static const size_t OFF_G2  = 38928384;    // 64*1024 f32
static const size_t OFF_S   = 39190528;    // 3*1024 f32
static const size_t OFF_C   = 39202816;    // 256 u32 counters

__device__ inline float wsum(float v) {
#pragma unroll
    for (int m = 32; m >= 1; m >>= 1) v += __shfl_xor(v, m, 64);
    return v;
}

__device__ inline unsigned ticket(unsigned* c) {
    return __hip_atomic_fetch_add(c, 1u, __ATOMIC_ACQ_REL, __HIP_MEMORY_SCOPE_AGENT);
}

// ---------------------------------------------------------------------------
// prep: [0,3072) feats/queue row norms -> A16 (4 rows/block)
//       [3072,3104) head: 8 k-rows/block -> transposed normalized f16 Bf
//       [3104] zero reduction counters
__global__ __launch_bounds__(256)
void prep_k(const float* __restrict__ feats, const float* __restrict__ queue,
            const float* __restrict__ head, f16* __restrict__ A16,
            f16* __restrict__ Bf, unsigned* __restrict__ cnt) {
    int b = blockIdx.x, tid = threadIdx.x;
    int wave = tid >> 6, lane = tid & 63;
    if (b < 3072) {
        int row = b * 4 + wave;
        const float* src = (row < NFEAT) ? feats + (size_t)row * DDIM
                                         : queue + (size_t)(row - NFEAT) * DDIM;
        float4 v = *(const float4*)(src + lane * 4);
        float s = wsum(v.x * v.x + v.y * v.y + v.z * v.z + v.w * v.w);
        float inv = 1.0f / sqrtf(fmaxf(s, 1e-24f));
        f16x4 o = { (f16)(v.x * inv), (f16)(v.y * inv), (f16)(v.z * inv), (f16)(v.w * inv) };
        *(f16x4*)(A16 + (size_t)row * DDIM + lane * 4) = o;
    } else if (b < 3104) {
        __shared__ float rin[8];
        int kb = (b - 3072) * 8;
        for (int j = 0; j < 2; ++j) {
            int k = kb + wave * 2 + j;
            const float* hr = head + (size_t)k * KDIM;
            float s = 0.f;
            for (int n = lane; n < KDIM; n += 64) { float v = hr[n]; s += v * v; }
            s = wsum(s);
            if (lane == 0) rin[wave * 2 + j] = 1.0f / sqrtf(fmaxf(s, 1e-24f));
        }
        __syncthreads();
        float r[8];
#pragma unroll
        for (int i = 0; i < 8; ++i) r[i] = rin[i];
        for (int n = tid; n < KDIM; n += 256) {
            f16 tmp[8];
#pragma unroll
            for (int i = 0; i < 8; ++i)
                tmp[i] = (f16)(head[(size_t)(kb + i) * KDIM + n] * r[i]);
            *(uint4*)(Bf + (size_t)n * DDIM + kb) = *(const uint4*)(tmp);
        }
    } else {
        cnt[tid] = 0u;
    }
}

// ---------------------------------------------------------------------------
// MFMA GEMM + exp + f16 E store + colsum partial -> P0[by][col];
// LAST block reduces P0 -> S0 (saves a dispatch).
__global__ __launch_bounds__(256, 3)
void gemm_exp_k(const f16* __restrict__ A16, const f16* __restrict__ Bf,
                f16* __restrict__ E16, float* __restrict__ P0,
                unsigned* __restrict__ cntG, float* __restrict__ S0) {
    __shared__ __align__(16) char smem[34816];
    __shared__ unsigned lastFlag;
    f16 (*Es)[136] = (f16(*)[136])smem;
    int tid = threadIdx.x;
    int wave = tid >> 6, lane = tid & 63;
    int lm = lane & 15, q = lane >> 4;
    int row0 = blockIdx.y * 128, col0 = blockIdx.x * 128;
    int wm = (wave >> 1) * 64, wn = (wave & 1) * 64;
    const f16* Ab = A16 + (size_t)(row0 + wm + lm) * DDIM + q * 8;
    const f16* Bb = Bf  + (size_t)(col0 + wn + lm) * DDIM + q * 8;

    f32x4 acc[4][4];
#pragma unroll
    for (int i = 0; i < 4; ++i)
#pragma unroll
        for (int j = 0; j < 4; ++j) acc[i][j] = (f32x4){0.f, 0.f, 0.f, 0.f};

#pragma unroll
    for (int kt = 0; kt < DDIM; kt += 32) {
        f16x8 a[4], b[4];
#pragma unroll
        for (int ms = 0; ms < 4; ++ms) a[ms] = *(const f16x8*)(Ab + (size_t)ms * 16 * DDIM + kt);
#pragma unroll
        for (int ns = 0; ns < 4; ++ns) b[ns] = *(const f16x8*)(Bb + (size_t)ns * 16 * DDIM + kt);
#pragma unroll
        for (int ms = 0; ms < 4; ++ms)
#pragma unroll
            for (int ns = 0; ns < 4; ++ns)
                acc[ms][ns] = __builtin_amdgcn_mfma_f32_16x16x32_f16(a[ms], b[ns], acc[ms][ns], 0, 0, 0);
    }

    float colp[4] = {0.f, 0.f, 0.f, 0.f};
#pragma unroll
    for (int ms = 0; ms < 4; ++ms) {
#pragma unroll
        for (int ns = 0; ns < 4; ++ns) {
            int gc = col0 + wn + ns * 16 + lm;
            bool ok = gc < KDIM;
#pragma unroll
            for (int r = 0; r < 4; ++r) {
                float e = ok ? __expf(acc[ms][ns][r] * 20.0f) : 0.0f;
                colp[ns] += e;
                Es[wm + ms * 16 + q * 4 + r][wn + ns * 16 + lm] = (f16)e;
            }
        }
    }
#pragma unroll
    for (int ns = 0; ns < 4; ++ns) {
        colp[ns] += __shfl_xor(colp[ns], 16, 64);
        colp[ns] += __shfl_xor(colp[ns], 32, 64);
    }
    __syncthreads();
    {
        int r = tid >> 1, half = tid & 1;
        const f16* src = &Es[r][half * 64];
        f16* dst = E16 + (size_t)(row0 + r) * KPAD + col0 + half * 64;
#pragma unroll
        for (int i = 0; i < 8; ++i)
            *(uint4*)(dst + i * 8) = *(const uint4*)(src + i * 8);
    }
    __syncthreads();
    float* cred = (float*)smem;
    if (tid < 128) cred[tid] = 0.f;
    __syncthreads();
    if (lane < 16) {
#pragma unroll
        for (int ns = 0; ns < 4; ++ns)
            atomicAdd(&cred[wn + ns * 16 + lane], colp[ns]);
    }
    __syncthreads();
    if (tid < 128) P0[(size_t)blockIdx.y * KPAD + col0 + tid] = cred[tid];

    // ---- last-block reduction P0 -> S0 ----
    __threadfence();
    __syncthreads();
    if (tid == 0) lastFlag = (ticket(cntG) == 767u);
    __syncthreads();
    if (!lastFlag) return;
    __threadfence();
    float s0 = 0.f, s1 = 0.f, s2 = 0.f, s3 = 0.f;
#pragma unroll 8
    for (int t = 0; t < 96; ++t) {
        const float* row = P0 + (size_t)t * KPAD;
        s0 += row[tid]; s1 += row[tid + 256];
        s2 += row[tid + 512]; s3 += row[tid + 768];
    }
    S0[tid] = s0; S0[tid + 256] = s1; S0[tid + 512] = s2; S0[tid + 768] = s3;
}

// ---------------------------------------------------------------------------
// rowpass: r[k]=1/(1000*Sin[k]); c[b]=1/(12288*dot(E[b,:],r));
// block partial colsum -> Pout[bid]; two-level last-block tree reduces to Sout.
// 768 blocks x 16 rows; groups of 12 -> G[64] -> Sout.
__global__ __launch_bounds__(256)
void rowpass_k(const f16* __restrict__ E16, const float* __restrict__ Sin,
               float* __restrict__ Pout, float* __restrict__ G,
               unsigned* __restrict__ cntA, unsigned* __restrict__ cntB,
               float* __restrict__ Sout) {
    __shared__ float rl[KPAD];
    __shared__ float cols4[4][KPAD];
    __shared__ unsigned lastA, lastB;
    int tid = threadIdx.x, bid = blockIdx.x;
    for (int n = tid; n < KPAD; n += 256)
        rl[n] = (n < KDIM) ? 1.0f / (1000.0f * Sin[n]) : 0.0f;
    __syncthreads();
    int wave = tid >> 6, lane = tid & 63;
    int n0 = lane * 16;
    float rv[16];
#pragma unroll
    for (int i = 0; i < 16; ++i) rv[i] = rl[n0 + i];
    float ca[16];
#pragma unroll
    for (int i = 0; i < 16; ++i) ca[i] = 0.f;
    int rowbase = bid * 16 + wave * 4;
#pragma unroll
    for (int j = 0; j < 4; ++j) {
        const f16* er = E16 + (size_t)(rowbase + j) * KPAD + n0;
        f16x8 e0 = *(const f16x8*)er;
        f16x8 e1 = *(const f16x8*)(er + 8);
        float ev[16];
#pragma unroll
        for (int i = 0; i < 8; ++i) { ev[i] = (float)e0[i]; ev[8 + i] = (float)e1[i]; }
        float p = 0.f;
#pragma unroll
        for (int i = 0; i < 16; ++i) p += ev[i] * rv[i];
        p = wsum(p);
        float c = 1.0f / (12288.0f * p);
#pragma unroll
        for (int i = 0; i < 16; ++i) ca[i] += ev[i] * c;
    }
#pragma unroll
    for (int i = 0; i < 16; ++i) {
        int idx = (i + lane) & 15;
        cols4[wave][n0 + idx] = ca[idx];
    }
    __syncthreads();
    for (int n = tid; n < KPAD; n += 256)
        Pout[(size_t)bid * KPAD + n] =
            cols4[0][n] + cols4[1][n] + cols4[2][n] + cols4[3][n];

    // ---- level 1: last of each 12-block group reduces to G[g] ----
    int g = bid / 12;
    __threadfence();
    __syncthreads();
    if (tid == 0) lastA = (ticket(&cntA[g]) == 11u);
    __syncthreads();
    if (!lastA) return;
    __threadfence();
    {
        const float* base = Pout + (size_t)g * 12 * KPAD;
        float s0 = 0.f, s1 = 0.f, s2 = 0.f, s3 = 0.f;
#pragma unroll
        for (int t = 0; t < 12; ++t) {
            const float* row = base + (size_t)t * KPAD;
            s0 += row[tid]; s1 += row[tid + 256];
            s2 += row[tid + 512]; s3 += row[tid + 768];
        }
        float* go = G + (size_t)g * KPAD;
        go[tid] = s0; go[tid + 256] = s1; go[tid + 512] = s2; go[tid + 768] = s3;
    }
    // ---- level 2: last of 64 groups reduces G -> Sout ----
    __threadfence();
    __syncthreads();
    if (tid == 0) lastB = (ticket(cntB) == 63u);
    __syncthreads();
    if (!lastB) return;
    __threadfence();
    {
        float s0 = 0.f, s1 = 0.f, s2 = 0.f, s3 = 0.f;
#pragma unroll 8
        for (int t = 0; t < 64; ++t) {
            const float* row = G + (size_t)t * KPAD;
            s0 += row[tid]; s1 += row[tid + 256];
            s2 += row[tid + 512]; s3 += row[tid + 768];
        }
        Sout[tid] = s0; Sout[tid + 256] = s1;
        Sout[tid + 512] = s2; Sout[tid + 768] = s3;
    }
}

// ---------------------------------------------------------------------------
// out[b,:] = E[b,:]*r / dot(E[b,:], r) for rows < 4096. 1 row per wave.
__global__ __launch_bounds__(256)
void out_k(const f16* __restrict__ E16, const float* __restrict__ S2,
           float* __restrict__ out) {
    __shared__ float rl[KPAD];
    int tid = threadIdx.x;
    for (int n = tid; n < KPAD; n += 256)
        rl[n] = (n < KDIM) ? 1.0f / (1000.0f * S2[n]) : 0.0f;
    __syncthreads();
    int wave = tid >> 6, lane = tid & 63;
    int n0 = lane * 16;
    float rv[16];
#pragma unroll
    for (int i = 0; i < 16; ++i) rv[i] = rl[n0 + i];
    int row = blockIdx.x * 4 + wave;
    const f16* er = E16 + (size_t)row * KPAD + n0;
    f16x8 e0 = *(const f16x8*)er;
    f16x8 e1 = *(const f16x8*)(er + 8);
    float w[16];
    float p = 0.f;
#pragma unroll
    for (int i = 0; i < 8; ++i) {
        w[i] = (float)e0[i] * rv[i];
        w[8 + i] = (float)e1[i] * rv[8 + i];
    }
#pragma unroll
    for (int i = 0; i < 16; ++i) p += w[i];
    p = wsum(p);
    float inv = 1.0f / p;
    float* orow = out + (size_t)row * KDIM;
#pragma unroll
    for (int i = 0; i < 16; i += 4) {
        int n = n0 + i;
        if (n + 3 < KDIM) {
            float4 o = { w[i] * inv, w[i + 1] * inv, w[i + 2] * inv, w[i + 3] * inv };
            *(float4*)(orow + n) = o;
        } else {
#pragma unroll
            for (int t = 0; t < 4; ++t)
                if (n + t < KDIM) orow[n + t] = w[i + t] * inv;
        }
    }
}

// ---------------------------------------------------------------------------
extern "C" void kernel_launch(void* const* d_in, const int* in_sizes, int n_in,
                              void* d_out, int out_size, void* d_ws, size_t ws_size,
                              hipStream_t stream) {
    (void)in_sizes; (void)n_in; (void)out_size; (void)ws_size;
    const float* feats = (const float*)d_in[0];   // [4096,256]
    const float* head  = (const float*)d_in[1];   // [256,1000]
    const float* queue = (const float*)d_in[2];   // [8192,256]
    float* out = (float*)d_out;                   // [4096,1000]

    char* ws = (char*)d_ws;
    f16*      A16 = (f16*)(ws + OFF_A16);
    f16*      Bf  = (f16*)(ws + OFF_BF);
    f16*      E16 = (f16*)(ws + OFF_E16);
    float*    P0  = (float*)(ws + OFF_P0);
    float*    P1  = (float*)(ws + OFF_P1);
    float*    P2  = (float*)(ws + OFF_P2);
    float*    G1  = (float*)(ws + OFF_G1);
    float*    G2  = (float*)(ws + OFF_G2);
    float*    S   = (float*)(ws + OFF_S);
    unsigned* C   = (unsigned*)(ws + OFF_C);
    float* S0 = S;
    float* S1 = S + KPAD;
    float* S2 = S + 2 * KPAD;
    unsigned* cntG  = C + 0;
    unsigned* cntB1 = C + 1;
    unsigned* cntB2 = C + 2;
    unsigned* cntA1 = C + 64;
    unsigned* cntA2 = C + 128;

    prep_k<<<3105, 256, 0, stream>>>(feats, queue, head, A16, Bf, C);
    gemm_exp_k<<<dim3(8, 96), 256, 0, stream>>>(A16, Bf, E16, P0, cntG, S0);
    rowpass_k<<<768, 256, 0, stream>>>(E16, S0, P1, G1, cntA1, cntB1, S1);
    rowpass_k<<<768, 256, 0, stream>>>(E16, S1, P2, G2, cntA2, cntB2, S2);
    out_k<<<NFEAT / 4, 256, 0, stream>>>(E16, S2, out);
}

// Round 10
// 144.111 us; speedup vs baseline: 3.7022x; 3.7022x over previous
//
#include <hip/hip_runtime.h>
#include <math.h>

typedef _Float16 f16;
typedef _Float16 f16x8 __attribute__((ext_vector_type(8)));
typedef _Float16 f16x4 __attribute__((ext_vector_type(4)));
typedef float f32x4 __attribute__((ext_vector_type(4)));

#define NROWS 12288
#define NFEAT 4096
#define DDIM  256
#define KDIM  1000
#define KPAD  1024
#define NSLAB 8

// workspace layout (bytes)
static const size_t OFF_A16 = 0;           // 12288*256 f16 = 6,291,456
static const size_t OFF_BF  = 6291456;     // 1024*256 f16  =   524,288
static const size_t OFF_E16 = 6815744;     // 12288*1024 f16= 25,165,824
static const size_t OFF_SL  = 31981568;    // 3 * 8 * 1024 f32 slabs = 98,304

__device__ inline float wsum(float v) {
#pragma unroll
    for (int m = 32; m >= 1; m >>= 1) v += __shfl_xor(v, m, 64);
    return v;
}

// ---------------------------------------------------------------------------
// prep: [0,3072)   feats/queue row norms -> A16 (4 rows/block)
//       [3072,3104) head: 8 k-rows/block -> transposed normalized f16 Bf
//       [3104,3128) zero the 3 slab accumulators (24 KPAD-rows of f32)
__global__ __launch_bounds__(256)
void prep_k(const float* __restrict__ feats, const float* __restrict__ queue,
            const float* __restrict__ head, f16* __restrict__ A16,
            f16* __restrict__ Bf, float* __restrict__ slabs) {
    int b = blockIdx.x, tid = threadIdx.x;
    int wave = tid >> 6, lane = tid & 63;
    if (b < 3072) {
        int row = b * 4 + wave;
        const float* src = (row < NFEAT) ? feats + (size_t)row * DDIM
                                         : queue + (size_t)(row - NFEAT) * DDIM;
        float4 v = *(const float4*)(src + lane * 4);
        float s = wsum(v.x * v.x + v.y * v.y + v.z * v.z + v.w * v.w);
        float inv = 1.0f / sqrtf(fmaxf(s, 1e-24f));
        f16x4 o = { (f16)(v.x * inv), (f16)(v.y * inv), (f16)(v.z * inv), (f16)(v.w * inv) };
        *(f16x4*)(A16 + (size_t)row * DDIM + lane * 4) = o;
    } else if (b < 3104) {
        __shared__ float rin[8];
        int kb = (b - 3072) * 8;
        for (int j = 0; j < 2; ++j) {
            int k = kb + wave * 2 + j;
            const float* hr = head + (size_t)k * KDIM;
            float s = 0.f;
            for (int n = lane; n < KDIM; n += 64) { float v = hr[n]; s += v * v; }
            s = wsum(s);
            if (lane == 0) rin[wave * 2 + j] = 1.0f / sqrtf(fmaxf(s, 1e-24f));
        }
        __syncthreads();
        float r[8];
#pragma unroll
        for (int i = 0; i < 8; ++i) r[i] = rin[i];
        for (int n = tid; n < KDIM; n += 256) {
            f16 tmp[8];
#pragma unroll
            for (int i = 0; i < 8; ++i)
                tmp[i] = (f16)(head[(size_t)(kb + i) * KDIM + n] * r[i]);
            *(uint4*)(Bf + (size_t)n * DDIM + kb) = *(const uint4*)(tmp);
        }
    } else {
        // zero slabs: 24 blocks x 1024 floats
        float* dst = slabs + (size_t)(b - 3104) * KPAD + tid * 4;
        *(float4*)dst = make_float4(0.f, 0.f, 0.f, 0.f);
    }
}

// ---------------------------------------------------------------------------
// MFMA GEMM + exp + f16 E store; LDS-combined colsum partial -> relaxed
// atomicAdd into S0 slab (blockIdx.y & 7). 128 atomics/block, depth 12.
__global__ __launch_bounds__(256, 3)
void gemm_exp_k(const f16* __restrict__ A16, const f16* __restrict__ Bf,
                f16* __restrict__ E16, float* __restrict__ S0sl) {
    __shared__ __align__(16) char smem[34816];
    f16 (*Es)[136] = (f16(*)[136])smem;
    int tid = threadIdx.x;
    int wave = tid >> 6, lane = tid & 63;
    int lm = lane & 15, q = lane >> 4;
    int row0 = blockIdx.y * 128, col0 = blockIdx.x * 128;
    int wm = (wave >> 1) * 64, wn = (wave & 1) * 64;
    const f16* Ab = A16 + (size_t)(row0 + wm + lm) * DDIM + q * 8;
    const f16* Bb = Bf  + (size_t)(col0 + wn + lm) * DDIM + q * 8;

    f32x4 acc[4][4];
#pragma unroll
    for (int i = 0; i < 4; ++i)
#pragma unroll
        for (int j = 0; j < 4; ++j) acc[i][j] = (f32x4){0.f, 0.f, 0.f, 0.f};

#pragma unroll
    for (int kt = 0; kt < DDIM; kt += 32) {
        f16x8 a[4], b[4];
#pragma unroll
        for (int ms = 0; ms < 4; ++ms) a[ms] = *(const f16x8*)(Ab + (size_t)ms * 16 * DDIM + kt);
#pragma unroll
        for (int ns = 0; ns < 4; ++ns) b[ns] = *(const f16x8*)(Bb + (size_t)ns * 16 * DDIM + kt);
#pragma unroll
        for (int ms = 0; ms < 4; ++ms)
#pragma unroll
            for (int ns = 0; ns < 4; ++ns)
                acc[ms][ns] = __builtin_amdgcn_mfma_f32_16x16x32_f16(a[ms], b[ns], acc[ms][ns], 0, 0, 0);
    }

    float colp[4] = {0.f, 0.f, 0.f, 0.f};
#pragma unroll
    for (int ms = 0; ms < 4; ++ms) {
#pragma unroll
        for (int ns = 0; ns < 4; ++ns) {
            int gc = col0 + wn + ns * 16 + lm;
            bool ok = gc < KDIM;
#pragma unroll
            for (int r = 0; r < 4; ++r) {
                float e = ok ? __expf(acc[ms][ns][r] * 20.0f) : 0.0f;
                colp[ns] += e;
                Es[wm + ms * 16 + q * 4 + r][wn + ns * 16 + lm] = (f16)e;
            }
        }
    }
#pragma unroll
    for (int ns = 0; ns < 4; ++ns) {
        colp[ns] += __shfl_xor(colp[ns], 16, 64);
        colp[ns] += __shfl_xor(colp[ns], 32, 64);
    }
    __syncthreads();
    {
        int r = tid >> 1, half = tid & 1;
        const f16* src = &Es[r][half * 64];
        f16* dst = E16 + (size_t)(row0 + r) * KPAD + col0 + half * 64;
#pragma unroll
        for (int i = 0; i < 8; ++i)
            *(uint4*)(dst + i * 8) = *(const uint4*)(src + i * 8);
    }
    __syncthreads();
    float* cred = (float*)smem;
    if (tid < 128) cred[tid] = 0.f;
    __syncthreads();
    if (lane < 16) {
#pragma unroll
        for (int ns = 0; ns < 4; ++ns)
            atomicAdd(&cred[wn + ns * 16 + lane], colp[ns]);   // LDS atomic
    }
    __syncthreads();
    if (tid < 128)
        atomicAdd(&S0sl[(size_t)(blockIdx.y & 7) * KPAD + col0 + tid], cred[tid]);
}

// ---------------------------------------------------------------------------
// rowpass: prologue folds 8-slab reduce of Sin -> rl; per-row
// c[b]=1/(12288*dot(E[b,:],r)); LDS-combined colsum partial -> relaxed
// atomicAdd into Sout slab (bid & 7). 768 blocks x 16 rows.
__global__ __launch_bounds__(256)
void rowpass_k(const f16* __restrict__ E16, const float* __restrict__ SinSl,
               float* __restrict__ SoutSl) {
    __shared__ float rl[KPAD];
    __shared__ float cols4[4][KPAD];
    int tid = threadIdx.x, bid = blockIdx.x;
    for (int n = tid; n < KPAD; n += 256) {
        float s = 0.f;
#pragma unroll
        for (int j = 0; j < NSLAB; ++j) s += SinSl[(size_t)j * KPAD + n];
        rl[n] = (n < KDIM) ? 1.0f / (1000.0f * s) : 0.0f;
    }
    __syncthreads();
    int wave = tid >> 6, lane = tid & 63;
    int n0 = lane * 16;
    float rv[16];
#pragma unroll
    for (int i = 0; i < 16; ++i) rv[i] = rl[n0 + i];
    float ca[16];
#pragma unroll
    for (int i = 0; i < 16; ++i) ca[i] = 0.f;
    int rowbase = bid * 16 + wave * 4;
#pragma unroll
    for (int j = 0; j < 4; ++j) {
        const f16* er = E16 + (size_t)(rowbase + j) * KPAD + n0;
        f16x8 e0 = *(const f16x8*)er;
        f16x8 e1 = *(const f16x8*)(er + 8);
        float ev[16];
#pragma unroll
        for (int i = 0; i < 8; ++i) { ev[i] = (float)e0[i]; ev[8 + i] = (float)e1[i]; }
        float p = 0.f;
#pragma unroll
        for (int i = 0; i < 16; ++i) p += ev[i] * rv[i];
        p = wsum(p);
        float c = 1.0f / (12288.0f * p);
#pragma unroll
        for (int i = 0; i < 16; ++i) ca[i] += ev[i] * c;
    }
#pragma unroll
    for (int i = 0; i < 16; ++i) {
        int idx = (i + lane) & 15;
        cols4[wave][n0 + idx] = ca[idx];
    }
    __syncthreads();
    float* outSlab = SoutSl + (size_t)(bid & 7) * KPAD;
    for (int n = tid; n < KPAD; n += 256)
        atomicAdd(&outSlab[n],
                  cols4[0][n] + cols4[1][n] + cols4[2][n] + cols4[3][n]);
}

// ---------------------------------------------------------------------------
// out: prologue folds 8-slab reduce of S2; out[b,:] = E[b,:]*r / rowsum.
// 1024 blocks, 1 row per wave, rows < 4096.
__global__ __launch_bounds__(256)
void out_k(const f16* __restrict__ E16, const float* __restrict__ S2sl,
           float* __restrict__ out) {
    __shared__ float rl[KPAD];
    int tid = threadIdx.x;
    for (int n = tid; n < KPAD; n += 256) {
        float s = 0.f;
#pragma unroll
        for (int j = 0; j < NSLAB; ++j) s += S2sl[(size_t)j * KPAD + n];
        rl[n] = (n < KDIM) ? 1.0f / (1000.0f * s) : 0.0f;
    }
    __syncthreads();
    int wave = tid >> 6, lane = tid & 63;
    int n0 = lane * 16;
    float rv[16];
#pragma unroll
    for (int i = 0; i < 16; ++i) rv[i] = rl[n0 + i];
    int row = blockIdx.x * 4 + wave;
    const f16* er = E16 + (size_t)row * KPAD + n0;
    f16x8 e0 = *(const f16x8*)er;
    f16x8 e1 = *(const f16x8*)(er + 8);
    float w[16];
    float p = 0.f;
#pragma unroll
    for (int i = 0; i < 8; ++i) {
        w[i] = (float)e0[i] * rv[i];
        w[8 + i] = (float)e1[i] * rv[8 + i];
    }
#pragma unroll
    for (int i = 0; i < 16; ++i) p += w[i];
    p = wsum(p);
    float inv = 1.0f / p;
    float* orow = out + (size_t)row * KDIM;
#pragma unroll
    for (int i = 0; i < 16; i += 4) {
        int n = n0 + i;
        if (n + 3 < KDIM) {
            float4 o = { w[i] * inv, w[i + 1] * inv, w[i + 2] * inv, w[i + 3] * inv };
            *(float4*)(orow + n) = o;
        } else {
#pragma unroll
            for (int t = 0; t < 4; ++t)
                if (n + t < KDIM) orow[n + t] = w[i + t] * inv;
        }
    }
}

// ---------------------------------------------------------------------------
extern "C" void kernel_launch(void* const* d_in, const int* in_sizes, int n_in,
                              void* d_out, int out_size, void* d_ws, size_t ws_size,
                              hipStream_t stream) {
    (void)in_sizes; (void)n_in; (void)out_size; (void)ws_size;
    const float* feats = (const float*)d_in[0];   // [4096,256]
    const float* head  = (const float*)d_in[1];   // [256,1000]
    const float* queue = (const float*)d_in[2];   // [8192,256]
    float* out = (float*)d_out;                   // [4096,1000]

    char* ws = (char*)d_ws;
    f16*   A16   = (f16*)(ws + OFF_A16);
    f16*   Bf    = (f16*)(ws + OFF_BF);
    f16*   E16   = (f16*)(ws + OFF_E16);
    float* slabs = (float*)(ws + OFF_SL);
    float* S0sl  = slabs;
    float* S1sl  = slabs + NSLAB * KPAD;
    float* S2sl  = slabs + 2 * NSLAB * KPAD;

    prep_k<<<3128, 256, 0, stream>>>(feats, queue, head, A16, Bf, slabs);
    gemm_exp_k<<<dim3(8, 96), 256, 0, stream>>>(A16, Bf, E16, S0sl);
    rowpass_k<<<768, 256, 0, stream>>>(E16, S0sl, S1sl);
    rowpass_k<<<768, 256, 0, stream>>>(E16, S1sl, S2sl);
    out_k<<<NFEAT / 4, 256, 0, stream>>>(E16, S2sl, out);
}